// Round 25
// baseline (484.971 us; speedup 1.0000x reference)
//
#include <hip/hip_runtime.h>

#define N_SUB 200000
#define N_GR  4096
#define DIM   256
#define HID   512
#define TCLS  10
#define MROWS 32             // 6250 * 32 = 200000 exactly; acc[2][4]=32 AGPR
#define RCAP  16384
#define RMARG 4e-3f          // fp16-path refine margin (> max mask err ~2e-3)
#define NREP  32             // S/Se replica count

typedef __attribute__((ext_vector_type(8))) _Float16 f16x8;
typedef __attribute__((ext_vector_type(4))) float f32x4;

__device__ __forceinline__ short bf16_rne(float x){
  unsigned u = __builtin_bit_cast(unsigned, x);
  unsigned r = (u + 0x7FFFu + ((u >> 16) & 1u)) >> 16;
  return (short)r;
}
__device__ __forceinline__ float bf16_to_f(short h){
  unsigned u = ((unsigned)(unsigned short)h) << 16;
  return __builtin_bit_cast(float, u);
}
__device__ __forceinline__ unsigned short f16_bits(float x){
  return __builtin_bit_cast(unsigned short, (_Float16)x);   // v_cvt_f16_f32, RNE
}
__device__ __forceinline__ float wave_reduce(float v){
  #pragma unroll
  for (int d = 1; d < 64; d <<= 1) v += __shfl_xor(v, d, 64);
  return v;
}
// swizzled fragment-major A granule index (16B granules = 8 halfs); ks 0..7, mt 0..1
__device__ __forceinline__ int a_gran(int mt, int mrow, int ks, int kgrp){
  return (((((mt*8 + ks)*4 + kgrp)*2 + (mrow>>3)) << 3)
          | ((mrow & 7) ^ ((ks & 3) << 1) ^ (kgrp & 1)));
}

// ---------------- bconv + fused init: W1 -> fragment-major fp16 ----------------
__global__ __launch_bounds__(256) void bconv_kernel(const float* __restrict__ W1,
                                                    unsigned short* __restrict__ bth,
                                                    int* cnt_all, float* S32, float* Se32,
                                                    float* S, float* Se,
                                                    int* counters, float* loss_p, int* rcnt){
  const int i = blockIdx.x*256 + threadIdx.x;
  if (i < N_GR) cnt_all[i] = 0;
  if (i < NREP*DIM){ S32[i] = 0.f; Se32[i] = 0.f; }
  if (i < DIM){ S[i] = 0.f; Se[i] = 0.f; }
  if (i < 64) loss_p[i] = 0.f;
  if (i < 2) counters[i] = 0;
  if (i == 0) rcnt[0] = 0;
  const int k = i >> 9;
  const int j = i & 511;
  const float x = W1[i];
  const int nt = j >> 4, mrow = j & 15;
  const int ksg = k >> 5, kgrp = (k >> 3) & 3, kk = k & 7;
  const int lane = kgrp*16 + mrow;
  const size_t dst = (((size_t)(nt*8 + ksg)*64 + lane) << 3) + kk;
  bth[dst] = f16_bits(x);
}

// ---------------- kernel A: single-plane fp16 MFMA, 32 rows/block ----------------
// 512 thr = 8 waves; K=256 LDS-resident fp16 (16 KB); 1 MFMA per (m,nt,ks).
__global__ __launch_bounds__(512, 4) void mask_gemm(
    const float* __restrict__ hsub, const unsigned short* __restrict__ bth,
    const float* __restrict__ b1, const float* __restrict__ W2,
    const float* __restrict__ b2, const int* __restrict__ s2g,
    float* __restrict__ mask_out, int* __restrict__ cnt_all,
    int* __restrict__ rlist, int* __restrict__ rcnt)
{
  __shared__ unsigned short a_f[8192];  // 16 KB swizzled fragment-major (32 rows x 256 k)
  __shared__ float sred[256];           // 1 KB -> 17 KB total
  const int tid = threadIdx.x;
  const int lane = tid & 63;
  const int q = tid >> 6;
  const int mrow = lane & 15;
  const int kgrp = lane >> 4;
  const int brow = blockIdx.x*MROWS;

  f32x4 acc[2][4];
  #pragma unroll
  for (int mt=0; mt<2; ++mt)
    #pragma unroll
    for (int nt=0; nt<4; ++nt) acc[mt][nt] = (f32x4){0.f,0.f,0.f,0.f};

  // ---- stage: 4 hoisted float4 loads per thread, fp32 -> fp16 ----
  const float* __restrict__ gbase = hsub + (size_t)brow*DIM;
  {
    float4 g[4];
    #pragma unroll
    for (int i = 0; i < 4; ++i){
      const int idx = i*512 + tid;               // float4 chunk 0..2047
      g[i] = *reinterpret_cast<const float4*>(gbase + (size_t)idx*4);
    }
    #pragma unroll
    for (int i = 0; i < 4; ++i){
      const int idx = i*512 + tid;
      const int rr = idx >> 6;                   // row 0..31
      const int ch = idx & 63;                   // full-K chunk 0..63
      const float4 v = g[i];
      const int so = a_gran(rr>>4, rr&15, ch>>3, (ch>>1)&3)*8 + (ch&1)*4;
      *reinterpret_cast<ushort4*>(&a_f[so]) =
          make_ushort4(f16_bits(v.x), f16_bits(v.y), f16_bits(v.z), f16_bits(v.w));
    }
  }
  __syncthreads();

  f16x8 Ah[2];
  #pragma unroll
  for (int ks = 0; ks < 8; ++ks){
    #pragma unroll
    for (int m = 0; m < 2; ++m){
      const int so = a_gran(m, mrow, ks, kgrp)*8;
      Ah[m] = *reinterpret_cast<const f16x8*>(&a_f[so]);
    }
    #pragma unroll
    for (int nt = 0; nt < 4; ++nt){
      const size_t bo = (((size_t)((q*4+nt)*8 + ks)*64 + lane) << 3);
      const f16x8 Bh = *reinterpret_cast<const f16x8*>(bth + bo);
      #pragma unroll
      for (int m = 0; m < 2; ++m)
        acc[m][nt] = __builtin_amdgcn_mfma_f32_16x16x32_f16(Ah[m], Bh, acc[m][nt], 0,0,0);
    }
  }

  // ---- epilogue: bias + ReLU + W2 dot; reduce 16 n-lanes; combine 8 waves ----
  float w2v[4], b1v[4];
  #pragma unroll
  for (int nt=0; nt<4; ++nt){
    const int n = q*64 + nt*16 + mrow;    // C: col = lane&15
    w2v[nt] = W2[n]; b1v[nt] = b1[n];
  }
  #pragma unroll
  for (int mt=0; mt<2; ++mt){
    #pragma unroll
    for (int r=0; r<4; ++r){
      float s = 0.f;
      #pragma unroll
      for (int nt=0; nt<4; ++nt)
        s += fmaxf(acc[mt][nt][r] + b1v[nt], 0.f) * w2v[nt];
      s += __shfl_xor(s, 1, 64);
      s += __shfl_xor(s, 2, 64);
      s += __shfl_xor(s, 4, 64);
      s += __shfl_xor(s, 8, 64);
      if (mrow == 0)
        sred[q*32 + mt*16 + kgrp*4 + r] = s;   // C: row = (lane>>4)*4 + reg
    }
  }
  __syncthreads();
  if (tid < MROWS){
    const int rr = brow + tid;
    float tot = b2[0];
    #pragma unroll
    for (int w = 0; w < 8; ++w) tot += sred[w*32 + tid];
    const float m = 1.f / (1.f + expf(-tot));
    mask_out[rr] = m;
    atomicAdd(&cnt_all[s2g[rr]], 1);
    if (fabsf(m - 0.4f) < RMARG || fabsf(m - 0.3f) < RMARG){
      const int p = atomicAdd(rcnt, 1);
      if (p < RCAP) rlist[p] = rr;
    }
  }
}

// ---------------- refine: exact fp32 logit, MLP-parallel ----------------
__global__ __launch_bounds__(512) void refine_kernel(
    const float* __restrict__ hsub, const float* __restrict__ W1,
    const float* __restrict__ b1, const float* __restrict__ W2,
    const float* __restrict__ b2, const int* __restrict__ rlist,
    const int* __restrict__ rcnt, float* __restrict__ mask_out)
{
  __shared__ float arow[256];
  __shared__ float red[512];
  const int n = min(rcnt[0], RCAP);
  const int t = threadIdx.x;            // j = t, 0..511
  for (int it = blockIdx.x; it < n; it += gridDim.x){
    const int row = rlist[it];
    if (t < 256) arow[t] = hsub[(size_t)row*DIM + t];
    __syncthreads();
    float y0 = b1[t], y1 = 0.f, y2 = 0.f, y3 = 0.f;
    #pragma unroll 8
    for (int k = 0; k < 64; ++k){
      y0 = fmaf(arow[k],     W1[(size_t)k*512 + t],         y0);
      y1 = fmaf(arow[k+64],  W1[(size_t)(k+64)*512 + t],    y1);
      y2 = fmaf(arow[k+128], W1[(size_t)(k+128)*512 + t],   y2);
      y3 = fmaf(arow[k+192], W1[(size_t)(k+192)*512 + t],   y3);
    }
    const float y = (y0 + y1) + (y2 + y3);
    red[t] = fmaxf(y, 0.f) * W2[t];
    __syncthreads();
    #pragma unroll
    for (int off = 256; off > 0; off >>= 1){
      if (t < off) red[t] += red[t+off];
      __syncthreads();
    }
    if (t == 0) mask_out[row] = 1.f / (1.f + expf(-(red[0] + b2[0])));
    __syncthreads();
  }
}

// ---------------- CSR build: scan + fill ----------------
__global__ __launch_bounds__(1024) void scan_kernel(const int* __restrict__ cnt,
                                                    int* __restrict__ offs,
                                                    int* __restrict__ cursor){
  __shared__ int buf[1024];
  const int t = threadIdx.x;
  const int c0 = cnt[t*4], c1 = cnt[t*4+1], c2 = cnt[t*4+2], c3 = cnt[t*4+3];
  const int s = c0+c1+c2+c3;
  buf[t] = s; __syncthreads();
  for (int d = 1; d < 1024; d <<= 1){
    int v = (t >= d) ? buf[t-d] : 0;
    __syncthreads();
    buf[t] += v;
    __syncthreads();
  }
  const int excl = buf[t] - s;
  const int o0 = excl, o1 = excl+c0, o2 = o1+c1, o3 = o2+c2;
  offs[t*4]=o0; offs[t*4+1]=o1; offs[t*4+2]=o2; offs[t*4+3]=o3;
  cursor[t*4]=o0; cursor[t*4+1]=o1; cursor[t*4+2]=o2; cursor[t*4+3]=o3;
  if (t == 1023) offs[4096] = buf[1023];
}

__global__ void fill_kernel(const int* __restrict__ s2g, int* __restrict__ cursor,
                            int* __restrict__ list){
  const int i = blockIdx.x*blockDim.x + threadIdx.x;
  if (i < N_SUB){
    const int g = s2g[i];
    const int p = atomicAdd(&cursor[g], 1);
    list[p] = i;
  }
}

// ---------------- kernel C: per-graph masked means (replica-spread atomics) ----------------
__global__ __launch_bounds__(256) void graph_means(
    const float* __restrict__ hsub, const float* __restrict__ mask,
    const int* __restrict__ list, const int* __restrict__ offs,
    const float* __restrict__ hgraph, const float* __restrict__ Wc,
    const float* __restrict__ bc, unsigned short* __restrict__ hatAb,
    float* __restrict__ S32, float* __restrict__ Se32,
    int* __restrict__ nzflags, int* __restrict__ counters,
    float* __restrict__ out)
{
  __shared__ int   sidx[256];
  __shared__ unsigned char sflag[256];
  __shared__ float wr4[4][4];
  __shared__ float wrc[TCLS][4];
  const int g = blockIdx.x;
  const int t = threadIdx.x;
  const int w = t >> 6, lane = t & 63;
  const int start = offs[g], end = offs[g+1];
  const int cnt = end - start;
  float sv = 0.f, sev = 0.f;
  int cv = 0, ce = 0;
  for (int base = 0; base < cnt; base += 256){
    const int nb = min(256, cnt - base);
    __syncthreads();
    if (t < nb){
      const int i = list[start + base + t];
      sidx[t] = i;
      const float m = mask[i];
      sflag[t] = (m > 0.4f) ? 1 : ((m <= 0.3f) ? 2 : 0);
    }
    __syncthreads();
    for (int p = 0; p < nb; p += 4){
      const int lim = nb - p;
      const int i0 = sidx[p];
      const int i1 = (lim > 1) ? sidx[p+1] : i0;
      const int i2 = (lim > 2) ? sidx[p+2] : i0;
      const int i3 = (lim > 3) ? sidx[p+3] : i0;
      const int f0 = sflag[p];
      const int f1 = (lim > 1) ? sflag[p+1] : 0;
      const int f2 = (lim > 2) ? sflag[p+2] : 0;
      const int f3 = (lim > 3) ? sflag[p+3] : 0;
      const float v0 = hsub[(size_t)i0*DIM + t];
      const float v1 = hsub[(size_t)i1*DIM + t];
      const float v2 = hsub[(size_t)i2*DIM + t];
      const float v3 = hsub[(size_t)i3*DIM + t];
      if (f0==1){ sv+=v0; cv++; } else if (f0==2){ sev+=v0; ce++; }
      if (f1==1){ sv+=v1; cv++; } else if (f1==2){ sev+=v1; ce++; }
      if (f2==1){ sv+=v2; cv++; } else if (f2==2){ sev+=v2; ce++; }
      if (f3==1){ sv+=v3; cv++; } else if (f3==2){ sev+=v3; ce++; }
    }
  }
  __syncthreads();
  const float aligned = sv  / fmaxf((float)cv, 1.f);
  const float envv    = sev / fmaxf((float)ce, 1.f);
  float r0 = wave_reduce(aligned*aligned);
  float r1 = wave_reduce(envv*envv);
  float r2 = wave_reduce(aligned != 0.f ? 1.f : 0.f);
  float r3 = wave_reduce(envv    != 0.f ? 1.f : 0.f);
  if (lane == 0){ wr4[w][0]=r0; wr4[w][1]=r1; wr4[w][2]=r2; wr4[w][3]=r3; }
  __syncthreads();
  const float an2  = wr4[0][0]+wr4[1][0]+wr4[2][0]+wr4[3][0];
  const float en2  = wr4[0][1]+wr4[1][1]+wr4[2][1]+wr4[3][1];
  const float nzpf = wr4[0][2]+wr4[1][2]+wr4[2][2]+wr4[3][2];
  const float nzef = wr4[0][3]+wr4[1][3]+wr4[2][3]+wr4[3][3];
  const bool nzp = nzpf > 0.f, nze = nzef > 0.f;
  const float an = fmaxf(sqrtf(an2), 1e-8f);
  const float en = fmaxf(sqrtf(en2), 1e-8f);
  const float ha = aligned / an;
  hatAb[(size_t)g*DIM + t] = (unsigned short)bf16_rne(ha);
  atomicAdd(&S32[((g & (NREP-1)) << 8) + t], ha);
  if (nze) atomicAdd(&Se32[((g & (NREP-1)) << 8) + t], envv / en);
  if (t == 0){
    nzflags[g] = nzp ? 1 : 0;
    if (nzp) atomicAdd(&counters[0], 1);
    if (nze) atomicAdd(&counters[1], 1);
  }
  const float hg = hgraph[(size_t)g*DIM + t];
  #pragma unroll
  for (int c = 0; c < TCLS; ++c){
    float part = hg*Wc[t*TCLS+c] + aligned*Wc[(DIM+t)*TCLS+c];
    part = wave_reduce(part);
    if (lane == 0) wrc[c][w] = part;
  }
  __syncthreads();
  if (t < TCLS)
    out[g*TCLS + t] = wrc[t][0]+wrc[t][1]+wrc[t][2]+wrc[t][3] + bc[t];
}

// ---------------- combine: fold S/Se replicas (16 blocks x 2 reps + atomic merge) ----------------
__global__ __launch_bounds__(256) void combine_kernel(const float* __restrict__ S32,
                                                      const float* __restrict__ Se32,
                                                      float* __restrict__ S,
                                                      float* __restrict__ Se){
  const int b = blockIdx.x;       // 0..15
  const int t = threadIdx.x;
  float s = 0.f, se = 0.f;
  #pragma unroll
  for (int r = 0; r < 2; ++r){
    s  += S32[(b*2 + r)*DIM + t];
    se += Se32[(b*2 + r)*DIM + t];
  }
  atomicAdd(&S[t], s);
  atomicAdd(&Se[t], se);
}

// ---------------- kernel D: contrastive loss via rank-1 identity ----------------
__global__ __launch_bounds__(256) void loss_kernel(
    const unsigned short* __restrict__ hatAb, const float* __restrict__ S,
    const float* __restrict__ Se, const int* __restrict__ nzflags,
    const int* __restrict__ counters, float* __restrict__ loss_p)
{
  __shared__ float wr[4][2];
  const int g = blockIdx.x, t = threadIdx.x;
  const int w = t >> 6, lane = t & 63;
  const float ha = bf16_to_f((short)hatAb[(size_t)g*DIM + t]);
  float p0 = wave_reduce(ha*S[t]);
  float p1 = wave_reduce(ha*Se[t]);
  if (lane == 0){ wr[w][0] = p0; wr[w][1] = p1; }
  __syncthreads();
  if (t == 0){
    const float dS  = wr[0][0]+wr[1][0]+wr[2][0]+wr[3][0];
    const float dSe = wr[0][1]+wr[1][1]+wr[2][1]+wr[3][1];
    const int nzp_cnt = counters[0];
    const int nenv = counters[1];
    const float pos_num = fmaxf((float)(nzp_cnt - 1), 1.f);
    const float positive = (4096.f - dS) / pos_num;
    const float negative = ((float)nenv - dSe) / fmaxf((float)nenv, 1.f);
    float contrib = fmaxf(positive - negative + 1.f, 0.f);
    contrib *= (nzflags[g] ? 1.f : 0.f) * ((nenv > 0) ? 1.f : 0.f);
    atomicAdd(&loss_p[g & 63], contrib * (1.f/4096.f));
  }
}

// ---------------- final: fold loss partials ----------------
__global__ void final_loss(const float* __restrict__ loss_p, float* __restrict__ loss){
  const int t = threadIdx.x;    // 64 threads
  float v = loss_p[t];
  v = wave_reduce(v);
  if (t == 0) loss[0] = v;
}

// ---------------- launch ----------------
extern "C" void kernel_launch(void* const* d_in, const int* in_sizes, int n_in,
                              void* d_out, int out_size, void* d_ws, size_t ws_size,
                              hipStream_t stream) {
  const float* h_graph = (const float*)d_in[0];
  const float* h_sub   = (const float*)d_in[1];
  const float* W1      = (const float*)d_in[2];
  const float* b1      = (const float*)d_in[3];
  const float* W2      = (const float*)d_in[4];
  const float* b2      = (const float*)d_in[5];
  const float* Wc      = (const float*)d_in[6];
  const float* bc      = (const float*)d_in[7];
  const int*   s2g     = (const int*)d_in[8];

  float* out  = (float*)d_out;          // [4096,10]
  float* loss = out + N_GR*TCLS;        // scalar
  float* mask = loss + 1;               // [200000]

  // workspace layout — ~3.4 MB (proven-safe envelope 5.06 MB)
  char* ws = (char*)d_ws;
  unsigned short* bth = (unsigned short*)ws;           // 256 KB (fp16 plane)
  unsigned short* hatAb = bth + HID*DIM;               // 2 MB
  int* cnt_all  = (int*)(hatAb + (size_t)N_GR*DIM);    // 4096
  int* offs     = cnt_all + N_GR;                      // 4097
  int* cursor   = offs + N_GR + 1;                     // 4096
  int* list     = cursor + N_GR;                       // 200000
  int* nzflags  = list + N_SUB;                        // 4096
  int* counters = nzflags + N_GR;                      // 2
  int* rcnt     = counters + 2;                        // 1
  int* rlist    = rcnt + 1;                            // 16384
  float* S      = (float*)(rlist + RCAP);              // 256
  float* Se     = S + DIM;                             // 256
  float* S32    = Se + DIM;                            // 32*256 (32 KB)
  float* Se32   = S32 + NREP*DIM;                      // 32*256 (32 KB)
  float* loss_p = Se32 + NREP*DIM;                     // 64

  hipLaunchKernelGGL(bconv_kernel, dim3(HID*DIM/256), dim3(256), 0, stream,
                     W1, bth, cnt_all, S32, Se32, S, Se, counters, loss_p, rcnt);
  hipLaunchKernelGGL(mask_gemm, dim3(N_SUB/MROWS), dim3(512), 0, stream,
                     h_sub, bth, b1, W2, b2, s2g, mask, cnt_all, rlist, rcnt);
  hipLaunchKernelGGL(refine_kernel, dim3(384), dim3(512), 0, stream,
                     h_sub, W1, b1, W2, b2, rlist, rcnt, mask);
  hipLaunchKernelGGL(scan_kernel, dim3(1), dim3(1024), 0, stream,
                     cnt_all, offs, cursor);
  hipLaunchKernelGGL(fill_kernel, dim3((N_SUB+255)/256), dim3(256), 0, stream,
                     s2g, cursor, list);
  hipLaunchKernelGGL(graph_means, dim3(N_GR), dim3(256), 0, stream,
                     h_sub, mask, list, offs, h_graph, Wc, bc,
                     hatAb, S32, Se32, nzflags, counters, out);
  hipLaunchKernelGGL(combine_kernel, dim3(16), dim3(256), 0, stream,
                     S32, Se32, S, Se);
  hipLaunchKernelGGL(loss_kernel, dim3(N_GR), dim3(256), 0, stream,
                     hatAb, S, Se, nzflags, counters, loss_p);
  hipLaunchKernelGGL(final_loss, dim3(1), dim3(64), 0, stream,
                     loss_p, loss);
}

// Round 26
// 450.140 us; speedup vs baseline: 1.0774x; 1.0774x over previous
//
#include <hip/hip_runtime.h>

#define N_SUB 200000
#define N_GR  4096
#define DIM   256
#define HID   512
#define TCLS  10
#define MROWS 32             // 6250 * 32 = 200000 exactly; acc[2][4]=32 AGPR
#define RCAP  16384
#define RMARG 4e-3f          // fp16-path refine margin (> max mask err ~2e-3)
#define NREP  32             // S/Se replica count

typedef __attribute__((ext_vector_type(8))) _Float16 f16x8;
typedef __attribute__((ext_vector_type(4))) float f32x4;

__device__ __forceinline__ short bf16_rne(float x){
  unsigned u = __builtin_bit_cast(unsigned, x);
  unsigned r = (u + 0x7FFFu + ((u >> 16) & 1u)) >> 16;
  return (short)r;
}
__device__ __forceinline__ float bf16_to_f(short h){
  unsigned u = ((unsigned)(unsigned short)h) << 16;
  return __builtin_bit_cast(float, u);
}
__device__ __forceinline__ unsigned short f16_bits(float x){
  return __builtin_bit_cast(unsigned short, (_Float16)x);   // v_cvt_f16_f32, RNE
}
__device__ __forceinline__ float wave_reduce(float v){
  #pragma unroll
  for (int d = 1; d < 64; d <<= 1) v += __shfl_xor(v, d, 64);
  return v;
}
// swizzled fragment-major A granule index (16B granules = 8 halfs); ks 0..7, mt 0..1
__device__ __forceinline__ int a_gran(int mt, int mrow, int ks, int kgrp){
  return (((((mt*8 + ks)*4 + kgrp)*2 + (mrow>>3)) << 3)
          | ((mrow & 7) ^ ((ks & 3) << 1) ^ (kgrp & 1)));
}

// ---------------- bconv + fused init: W1 -> fragment-major fp16 ----------------
__global__ __launch_bounds__(256) void bconv_kernel(const float* __restrict__ W1,
                                                    unsigned short* __restrict__ bth,
                                                    int* cnt_all, float* S32, float* Se32,
                                                    float* S, float* Se,
                                                    int* counters, float* loss_p, int* rcnt){
  const int i = blockIdx.x*256 + threadIdx.x;
  if (i < N_GR) cnt_all[i] = 0;
  if (i < NREP*DIM){ S32[i] = 0.f; Se32[i] = 0.f; }
  if (i < DIM){ S[i] = 0.f; Se[i] = 0.f; }
  if (i < 64) loss_p[i] = 0.f;
  if (i < 2) counters[i] = 0;
  if (i == 0) rcnt[0] = 0;
  const int k = i >> 9;
  const int j = i & 511;
  const float x = W1[i];
  const int nt = j >> 4, mrow = j & 15;
  const int ksg = k >> 5, kgrp = (k >> 3) & 3, kk = k & 7;
  const int lane = kgrp*16 + mrow;
  const size_t dst = (((size_t)(nt*8 + ksg)*64 + lane) << 3) + kk;
  bth[dst] = f16_bits(x);
}

// ---------------- kernel A: single-plane fp16 MFMA, 32 rows/block ----------------
__global__ __launch_bounds__(512, 4) void mask_gemm(
    const float* __restrict__ hsub, const unsigned short* __restrict__ bth,
    const float* __restrict__ b1, const float* __restrict__ W2,
    const float* __restrict__ b2, const int* __restrict__ s2g,
    float* __restrict__ mask_out, int* __restrict__ cnt_all,
    int* __restrict__ rlist, int* __restrict__ rcnt)
{
  __shared__ unsigned short a_f[8192];  // 16 KB swizzled fragment-major (32 rows x 256 k)
  __shared__ float sred[256];           // 1 KB -> 17 KB total
  const int tid = threadIdx.x;
  const int lane = tid & 63;
  const int q = tid >> 6;
  const int mrow = lane & 15;
  const int kgrp = lane >> 4;
  const int brow = blockIdx.x*MROWS;

  f32x4 acc[2][4];
  #pragma unroll
  for (int mt=0; mt<2; ++mt)
    #pragma unroll
    for (int nt=0; nt<4; ++nt) acc[mt][nt] = (f32x4){0.f,0.f,0.f,0.f};

  // ---- stage: 4 hoisted float4 loads per thread, fp32 -> fp16 ----
  const float* __restrict__ gbase = hsub + (size_t)brow*DIM;
  {
    float4 g[4];
    #pragma unroll
    for (int i = 0; i < 4; ++i){
      const int idx = i*512 + tid;               // float4 chunk 0..2047
      g[i] = *reinterpret_cast<const float4*>(gbase + (size_t)idx*4);
    }
    #pragma unroll
    for (int i = 0; i < 4; ++i){
      const int idx = i*512 + tid;
      const int rr = idx >> 6;                   // row 0..31
      const int ch = idx & 63;                   // full-K chunk 0..63
      const float4 v = g[i];
      const int so = a_gran(rr>>4, rr&15, ch>>3, (ch>>1)&3)*8 + (ch&1)*4;
      *reinterpret_cast<ushort4*>(&a_f[so]) =
          make_ushort4(f16_bits(v.x), f16_bits(v.y), f16_bits(v.z), f16_bits(v.w));
    }
  }
  __syncthreads();

  f16x8 Ah[2];
  #pragma unroll
  for (int ks = 0; ks < 8; ++ks){
    #pragma unroll
    for (int m = 0; m < 2; ++m){
      const int so = a_gran(m, mrow, ks, kgrp)*8;
      Ah[m] = *reinterpret_cast<const f16x8*>(&a_f[so]);
    }
    #pragma unroll
    for (int nt = 0; nt < 4; ++nt){
      const size_t bo = (((size_t)((q*4+nt)*8 + ks)*64 + lane) << 3);
      const f16x8 Bh = *reinterpret_cast<const f16x8*>(bth + bo);
      #pragma unroll
      for (int m = 0; m < 2; ++m)
        acc[m][nt] = __builtin_amdgcn_mfma_f32_16x16x32_f16(Ah[m], Bh, acc[m][nt], 0,0,0);
    }
  }

  // ---- epilogue: bias + ReLU + W2 dot; reduce 16 n-lanes; combine 8 waves ----
  float w2v[4], b1v[4];
  #pragma unroll
  for (int nt=0; nt<4; ++nt){
    const int n = q*64 + nt*16 + mrow;    // C: col = lane&15
    w2v[nt] = W2[n]; b1v[nt] = b1[n];
  }
  #pragma unroll
  for (int mt=0; mt<2; ++mt){
    #pragma unroll
    for (int r=0; r<4; ++r){
      float s = 0.f;
      #pragma unroll
      for (int nt=0; nt<4; ++nt)
        s += fmaxf(acc[mt][nt][r] + b1v[nt], 0.f) * w2v[nt];
      s += __shfl_xor(s, 1, 64);
      s += __shfl_xor(s, 2, 64);
      s += __shfl_xor(s, 4, 64);
      s += __shfl_xor(s, 8, 64);
      if (mrow == 0)
        sred[q*32 + mt*16 + kgrp*4 + r] = s;   // C: row = (lane>>4)*4 + reg
    }
  }
  __syncthreads();
  if (tid < MROWS){
    const int rr = brow + tid;
    float tot = b2[0];
    #pragma unroll
    for (int w = 0; w < 8; ++w) tot += sred[w*32 + tid];
    const float m = 1.f / (1.f + expf(-tot));
    mask_out[rr] = m;
    atomicAdd(&cnt_all[s2g[rr]], 1);
    if (fabsf(m - 0.4f) < RMARG || fabsf(m - 0.3f) < RMARG){
      const int p = atomicAdd(rcnt, 1);
      if (p < RCAP) rlist[p] = rr;
    }
  }
}

// ---------------- refine: exact fp32 logit, ONE ROW PER WAVE (8 rows/block) ----------------
// lane owns 8 hidden units; arow broadcast from per-wave LDS slice; W1 rows coalesced 2KB.
__global__ __launch_bounds__(512) void refine_kernel(
    const float* __restrict__ hsub, const float* __restrict__ W1,
    const float* __restrict__ b1, const float* __restrict__ W2,
    const float* __restrict__ b2, const int* __restrict__ rlist,
    const int* __restrict__ rcnt, float* __restrict__ mask_out)
{
  __shared__ float arow[8][260];        // per-wave row slice (pad)
  const int t = threadIdx.x;
  const int lane = t & 63, w = t >> 6;
  const int n = min(rcnt[0], RCAP);
  const int stride = gridDim.x*8;
  const int nit = (n + stride - 1)/stride;
  for (int i2 = 0; i2 < nit; ++i2){
    const int it = i2*stride + blockIdx.x*8 + w;
    const bool act = it < n;
    const int row = act ? rlist[it] : 0;
    if (act){
      const float4 v = *reinterpret_cast<const float4*>(hsub + (size_t)row*DIM + lane*4);
      *reinterpret_cast<float4*>(&arow[w][lane*4]) = v;
    }
    __syncthreads();
    float y[8];
    #pragma unroll
    for (int u = 0; u < 8; ++u) y[u] = b1[lane*8 + u];
    if (act){
      #pragma unroll 4
      for (int k = 0; k < 256; ++k){
        const float a = arow[w][k];
        const float4 w0 = *reinterpret_cast<const float4*>(W1 + (size_t)k*512 + lane*8);
        const float4 w1 = *reinterpret_cast<const float4*>(W1 + (size_t)k*512 + lane*8 + 4);
        y[0] = fmaf(a, w0.x, y[0]); y[1] = fmaf(a, w0.y, y[1]);
        y[2] = fmaf(a, w0.z, y[2]); y[3] = fmaf(a, w0.w, y[3]);
        y[4] = fmaf(a, w1.x, y[4]); y[5] = fmaf(a, w1.y, y[5]);
        y[6] = fmaf(a, w1.z, y[6]); y[7] = fmaf(a, w1.w, y[7]);
      }
    }
    float s = 0.f;
    #pragma unroll
    for (int u = 0; u < 8; ++u) s += fmaxf(y[u], 0.f) * W2[lane*8 + u];
    s = wave_reduce(s);
    if (act && lane == 0)
      mask_out[row] = 1.f / (1.f + expf(-(s + b2[0])));
    __syncthreads();
  }
}

// ---------------- CSR build: scan + fill ----------------
__global__ __launch_bounds__(1024) void scan_kernel(const int* __restrict__ cnt,
                                                    int* __restrict__ offs,
                                                    int* __restrict__ cursor){
  __shared__ int buf[1024];
  const int t = threadIdx.x;
  const int c0 = cnt[t*4], c1 = cnt[t*4+1], c2 = cnt[t*4+2], c3 = cnt[t*4+3];
  const int s = c0+c1+c2+c3;
  buf[t] = s; __syncthreads();
  for (int d = 1; d < 1024; d <<= 1){
    int v = (t >= d) ? buf[t-d] : 0;
    __syncthreads();
    buf[t] += v;
    __syncthreads();
  }
  const int excl = buf[t] - s;
  const int o0 = excl, o1 = excl+c0, o2 = o1+c1, o3 = o2+c2;
  offs[t*4]=o0; offs[t*4+1]=o1; offs[t*4+2]=o2; offs[t*4+3]=o3;
  cursor[t*4]=o0; cursor[t*4+1]=o1; cursor[t*4+2]=o2; cursor[t*4+3]=o3;
  if (t == 1023) offs[4096] = buf[1023];
}

__global__ void fill_kernel(const int* __restrict__ s2g, int* __restrict__ cursor,
                            int* __restrict__ list){
  const int i = blockIdx.x*blockDim.x + threadIdx.x;
  if (i < N_SUB){
    const int g = s2g[i];
    const int p = atomicAdd(&cursor[g], 1);
    list[p] = i;
  }
}

// ---------------- kernel C: per-graph masked means (replica-spread atomics) ----------------
__global__ __launch_bounds__(256) void graph_means(
    const float* __restrict__ hsub, const float* __restrict__ mask,
    const int* __restrict__ list, const int* __restrict__ offs,
    const float* __restrict__ hgraph, const float* __restrict__ Wc,
    const float* __restrict__ bc, unsigned short* __restrict__ hatAb,
    float* __restrict__ S32, float* __restrict__ Se32,
    int* __restrict__ nzflags, int* __restrict__ counters,
    float* __restrict__ out)
{
  __shared__ int   sidx[256];
  __shared__ unsigned char sflag[256];
  __shared__ float wr4[4][4];
  __shared__ float wrc[TCLS][4];
  const int g = blockIdx.x;
  const int t = threadIdx.x;
  const int w = t >> 6, lane = t & 63;
  const int start = offs[g], end = offs[g+1];
  const int cnt = end - start;
  float sv = 0.f, sev = 0.f;
  int cv = 0, ce = 0;
  for (int base = 0; base < cnt; base += 256){
    const int nb = min(256, cnt - base);
    __syncthreads();
    if (t < nb){
      const int i = list[start + base + t];
      sidx[t] = i;
      const float m = mask[i];
      sflag[t] = (m > 0.4f) ? 1 : ((m <= 0.3f) ? 2 : 0);
    }
    __syncthreads();
    for (int p = 0; p < nb; p += 4){
      const int lim = nb - p;
      const int i0 = sidx[p];
      const int i1 = (lim > 1) ? sidx[p+1] : i0;
      const int i2 = (lim > 2) ? sidx[p+2] : i0;
      const int i3 = (lim > 3) ? sidx[p+3] : i0;
      const int f0 = sflag[p];
      const int f1 = (lim > 1) ? sflag[p+1] : 0;
      const int f2 = (lim > 2) ? sflag[p+2] : 0;
      const int f3 = (lim > 3) ? sflag[p+3] : 0;
      const float v0 = hsub[(size_t)i0*DIM + t];
      const float v1 = hsub[(size_t)i1*DIM + t];
      const float v2 = hsub[(size_t)i2*DIM + t];
      const float v3 = hsub[(size_t)i3*DIM + t];
      if (f0==1){ sv+=v0; cv++; } else if (f0==2){ sev+=v0; ce++; }
      if (f1==1){ sv+=v1; cv++; } else if (f1==2){ sev+=v1; ce++; }
      if (f2==1){ sv+=v2; cv++; } else if (f2==2){ sev+=v2; ce++; }
      if (f3==1){ sv+=v3; cv++; } else if (f3==2){ sev+=v3; ce++; }
    }
  }
  __syncthreads();
  const float aligned = sv  / fmaxf((float)cv, 1.f);
  const float envv    = sev / fmaxf((float)ce, 1.f);
  float r0 = wave_reduce(aligned*aligned);
  float r1 = wave_reduce(envv*envv);
  float r2 = wave_reduce(aligned != 0.f ? 1.f : 0.f);
  float r3 = wave_reduce(envv    != 0.f ? 1.f : 0.f);
  if (lane == 0){ wr4[w][0]=r0; wr4[w][1]=r1; wr4[w][2]=r2; wr4[w][3]=r3; }
  __syncthreads();
  const float an2  = wr4[0][0]+wr4[1][0]+wr4[2][0]+wr4[3][0];
  const float en2  = wr4[0][1]+wr4[1][1]+wr4[2][1]+wr4[3][1];
  const float nzpf = wr4[0][2]+wr4[1][2]+wr4[2][2]+wr4[3][2];
  const float nzef = wr4[0][3]+wr4[1][3]+wr4[2][3]+wr4[3][3];
  const bool nzp = nzpf > 0.f, nze = nzef > 0.f;
  const float an = fmaxf(sqrtf(an2), 1e-8f);
  const float en = fmaxf(sqrtf(en2), 1e-8f);
  const float ha = aligned / an;
  hatAb[(size_t)g*DIM + t] = (unsigned short)bf16_rne(ha);
  atomicAdd(&S32[((g & (NREP-1)) << 8) + t], ha);
  if (nze) atomicAdd(&Se32[((g & (NREP-1)) << 8) + t], envv / en);
  if (t == 0){
    nzflags[g] = nzp ? 1 : 0;
    if (nzp) atomicAdd(&counters[0], 1);
    if (nze) atomicAdd(&counters[1], 1);
  }
  const float hg = hgraph[(size_t)g*DIM + t];
  #pragma unroll
  for (int c = 0; c < TCLS; ++c){
    float part = hg*Wc[t*TCLS+c] + aligned*Wc[(DIM+t)*TCLS+c];
    part = wave_reduce(part);
    if (lane == 0) wrc[c][w] = part;
  }
  __syncthreads();
  if (t < TCLS)
    out[g*TCLS + t] = wrc[t][0]+wrc[t][1]+wrc[t][2]+wrc[t][3] + bc[t];
}

// ---------------- combine: fold S/Se replicas (16 blocks x 2 reps + atomic merge) ----------------
__global__ __launch_bounds__(256) void combine_kernel(const float* __restrict__ S32,
                                                      const float* __restrict__ Se32,
                                                      float* __restrict__ S,
                                                      float* __restrict__ Se){
  const int b = blockIdx.x;       // 0..15
  const int t = threadIdx.x;
  float s = 0.f, se = 0.f;
  #pragma unroll
  for (int r = 0; r < 2; ++r){
    s  += S32[(b*2 + r)*DIM + t];
    se += Se32[(b*2 + r)*DIM + t];
  }
  atomicAdd(&S[t], s);
  atomicAdd(&Se[t], se);
}

// ---------------- kernel D: contrastive loss via rank-1 identity ----------------
__global__ __launch_bounds__(256) void loss_kernel(
    const unsigned short* __restrict__ hatAb, const float* __restrict__ S,
    const float* __restrict__ Se, const int* __restrict__ nzflags,
    const int* __restrict__ counters, float* __restrict__ loss_p)
{
  __shared__ float wr[4][2];
  const int g = blockIdx.x, t = threadIdx.x;
  const int w = t >> 6, lane = t & 63;
  const float ha = bf16_to_f((short)hatAb[(size_t)g*DIM + t]);
  float p0 = wave_reduce(ha*S[t]);
  float p1 = wave_reduce(ha*Se[t]);
  if (lane == 0){ wr[w][0] = p0; wr[w][1] = p1; }
  __syncthreads();
  if (t == 0){
    const float dS  = wr[0][0]+wr[1][0]+wr[2][0]+wr[3][0];
    const float dSe = wr[0][1]+wr[1][1]+wr[2][1]+wr[3][1];
    const int nzp_cnt = counters[0];
    const int nenv = counters[1];
    const float pos_num = fmaxf((float)(nzp_cnt - 1), 1.f);
    const float positive = (4096.f - dS) / pos_num;
    const float negative = ((float)nenv - dSe) / fmaxf((float)nenv, 1.f);
    float contrib = fmaxf(positive - negative + 1.f, 0.f);
    contrib *= (nzflags[g] ? 1.f : 0.f) * ((nenv > 0) ? 1.f : 0.f);
    atomicAdd(&loss_p[g & 63], contrib * (1.f/4096.f));
  }
}

// ---------------- final: fold loss partials ----------------
__global__ void final_loss(const float* __restrict__ loss_p, float* __restrict__ loss){
  const int t = threadIdx.x;    // 64 threads
  float v = loss_p[t];
  v = wave_reduce(v);
  if (t == 0) loss[0] = v;
}

// ---------------- launch ----------------
extern "C" void kernel_launch(void* const* d_in, const int* in_sizes, int n_in,
                              void* d_out, int out_size, void* d_ws, size_t ws_size,
                              hipStream_t stream) {
  const float* h_graph = (const float*)d_in[0];
  const float* h_sub   = (const float*)d_in[1];
  const float* W1      = (const float*)d_in[2];
  const float* b1      = (const float*)d_in[3];
  const float* W2      = (const float*)d_in[4];
  const float* b2      = (const float*)d_in[5];
  const float* Wc      = (const float*)d_in[6];
  const float* bc      = (const float*)d_in[7];
  const int*   s2g     = (const int*)d_in[8];

  float* out  = (float*)d_out;          // [4096,10]
  float* loss = out + N_GR*TCLS;        // scalar
  float* mask = loss + 1;               // [200000]

  // workspace layout — ~3.4 MB (proven-safe envelope 5.06 MB)
  char* ws = (char*)d_ws;
  unsigned short* bth = (unsigned short*)ws;           // 256 KB (fp16 plane)
  unsigned short* hatAb = bth + HID*DIM;               // 2 MB
  int* cnt_all  = (int*)(hatAb + (size_t)N_GR*DIM);    // 4096
  int* offs     = cnt_all + N_GR;                      // 4097
  int* cursor   = offs + N_GR + 1;                     // 4096
  int* list     = cursor + N_GR;                       // 200000
  int* nzflags  = list + N_SUB;                        // 4096
  int* counters = nzflags + N_GR;                      // 2
  int* rcnt     = counters + 2;                        // 1
  int* rlist    = rcnt + 1;                            // 16384
  float* S      = (float*)(rlist + RCAP);              // 256
  float* Se     = S + DIM;                             // 256
  float* S32    = Se + DIM;                            // 32*256 (32 KB)
  float* Se32   = S32 + NREP*DIM;                      // 32*256 (32 KB)
  float* loss_p = Se32 + NREP*DIM;                     // 64

  hipLaunchKernelGGL(bconv_kernel, dim3(HID*DIM/256), dim3(256), 0, stream,
                     W1, bth, cnt_all, S32, Se32, S, Se, counters, loss_p, rcnt);
  hipLaunchKernelGGL(mask_gemm, dim3(N_SUB/MROWS), dim3(512), 0, stream,
                     h_sub, bth, b1, W2, b2, s2g, mask, cnt_all, rlist, rcnt);
  hipLaunchKernelGGL(refine_kernel, dim3(384), dim3(512), 0, stream,
                     h_sub, W1, b1, W2, b2, rlist, rcnt, mask);
  hipLaunchKernelGGL(scan_kernel, dim3(1), dim3(1024), 0, stream,
                     cnt_all, offs, cursor);
  hipLaunchKernelGGL(fill_kernel, dim3((N_SUB+255)/256), dim3(256), 0, stream,
                     s2g, cursor, list);
  hipLaunchKernelGGL(graph_means, dim3(N_GR), dim3(256), 0, stream,
                     h_sub, mask, list, offs, h_graph, Wc, bc,
                     hatAb, S32, Se32, nzflags, counters, out);
  hipLaunchKernelGGL(combine_kernel, dim3(16), dim3(256), 0, stream,
                     S32, Se32, S, Se);
  hipLaunchKernelGGL(loss_kernel, dim3(N_GR), dim3(256), 0, stream,
                     hatAb, S, Se, nzflags, counters, loss_p);
  hipLaunchKernelGGL(final_loss, dim3(1), dim3(64), 0, stream,
                     loss_p, loss);
}

// Round 27
// 433.002 us; speedup vs baseline: 1.1200x; 1.0396x over previous
//
#include <hip/hip_runtime.h>

#define N_SUB 200000
#define N_GR  4096
#define DIM   256
#define HID   512
#define TCLS  10
#define MROWS 32             // 6250 * 32 = 200000 exactly; acc[2][4]=32 AGPR
#define RCAP  16384
#define RMARG 4e-3f          // fp16-path refine margin (> max mask err ~2e-3)
#define NREP  32             // S/Se replica count

typedef __attribute__((ext_vector_type(8))) _Float16 f16x8;
typedef __attribute__((ext_vector_type(4))) float f32x4;

__device__ __forceinline__ short bf16_rne(float x){
  unsigned u = __builtin_bit_cast(unsigned, x);
  unsigned r = (u + 0x7FFFu + ((u >> 16) & 1u)) >> 16;
  return (short)r;
}
__device__ __forceinline__ float bf16_to_f(short h){
  unsigned u = ((unsigned)(unsigned short)h) << 16;
  return __builtin_bit_cast(float, u);
}
__device__ __forceinline__ unsigned short f16_bits(float x){
  return __builtin_bit_cast(unsigned short, (_Float16)x);   // v_cvt_f16_f32, RNE
}
__device__ __forceinline__ float wave_reduce(float v){
  #pragma unroll
  for (int d = 1; d < 64; d <<= 1) v += __shfl_xor(v, d, 64);
  return v;
}
// swizzled fragment-major A granule index (16B granules = 8 halfs); ks 0..7, mt 0..1
__device__ __forceinline__ int a_gran(int mt, int mrow, int ks, int kgrp){
  return (((((mt*8 + ks)*4 + kgrp)*2 + (mrow>>3)) << 3)
          | ((mrow & 7) ^ ((ks & 3) << 1) ^ (kgrp & 1)));
}

// ---------------- bconv + fused init: W1 -> fragment-major fp16 ----------------
__global__ __launch_bounds__(256) void bconv_kernel(const float* __restrict__ W1,
                                                    unsigned short* __restrict__ bth,
                                                    int* cnt_all, float* S32, float* Se32,
                                                    float* S, float* Se,
                                                    int* counters, float* loss_p, int* rcnt){
  const int i = blockIdx.x*256 + threadIdx.x;
  if (i < N_GR) cnt_all[i] = 0;
  if (i < NREP*DIM){ S32[i] = 0.f; Se32[i] = 0.f; }
  if (i < DIM){ S[i] = 0.f; Se[i] = 0.f; }
  if (i < 64) loss_p[i] = 0.f;
  if (i < 2) counters[i] = 0;
  if (i == 0) rcnt[0] = 0;
  const int k = i >> 9;
  const int j = i & 511;
  const float x = W1[i];
  const int nt = j >> 4, mrow = j & 15;
  const int ksg = k >> 5, kgrp = (k >> 3) & 3, kk = k & 7;
  const int lane = kgrp*16 + mrow;
  const size_t dst = (((size_t)(nt*8 + ksg)*64 + lane) << 3) + kk;
  bth[dst] = f16_bits(x);
}

// ---------------- kernel A: single-plane fp16 MFMA, 32 rows/block ----------------
__global__ __launch_bounds__(512, 4) void mask_gemm(
    const float* __restrict__ hsub, const unsigned short* __restrict__ bth,
    const float* __restrict__ b1, const float* __restrict__ W2,
    const float* __restrict__ b2, const int* __restrict__ s2g,
    float* __restrict__ mask_out, int* __restrict__ cnt_all,
    int* __restrict__ rlist, int* __restrict__ rcnt)
{
  __shared__ unsigned short a_f[8192];  // 16 KB swizzled fragment-major (32 rows x 256 k)
  __shared__ float sred[256];           // 1 KB -> 17 KB total
  const int tid = threadIdx.x;
  const int lane = tid & 63;
  const int q = tid >> 6;
  const int mrow = lane & 15;
  const int kgrp = lane >> 4;
  const int brow = blockIdx.x*MROWS;

  f32x4 acc[2][4];
  #pragma unroll
  for (int mt=0; mt<2; ++mt)
    #pragma unroll
    for (int nt=0; nt<4; ++nt) acc[mt][nt] = (f32x4){0.f,0.f,0.f,0.f};

  // ---- stage: 4 hoisted float4 loads per thread, fp32 -> fp16 ----
  const float* __restrict__ gbase = hsub + (size_t)brow*DIM;
  {
    float4 g[4];
    #pragma unroll
    for (int i = 0; i < 4; ++i){
      const int idx = i*512 + tid;               // float4 chunk 0..2047
      g[i] = *reinterpret_cast<const float4*>(gbase + (size_t)idx*4);
    }
    #pragma unroll
    for (int i = 0; i < 4; ++i){
      const int idx = i*512 + tid;
      const int rr = idx >> 6;                   // row 0..31
      const int ch = idx & 63;                   // full-K chunk 0..63
      const float4 v = g[i];
      const int so = a_gran(rr>>4, rr&15, ch>>3, (ch>>1)&3)*8 + (ch&1)*4;
      *reinterpret_cast<ushort4*>(&a_f[so]) =
          make_ushort4(f16_bits(v.x), f16_bits(v.y), f16_bits(v.z), f16_bits(v.w));
    }
  }
  __syncthreads();

  f16x8 Ah[2];
  #pragma unroll
  for (int ks = 0; ks < 8; ++ks){
    #pragma unroll
    for (int m = 0; m < 2; ++m){
      const int so = a_gran(m, mrow, ks, kgrp)*8;
      Ah[m] = *reinterpret_cast<const f16x8*>(&a_f[so]);
    }
    #pragma unroll
    for (int nt = 0; nt < 4; ++nt){
      const size_t bo = (((size_t)((q*4+nt)*8 + ks)*64 + lane) << 3);
      const f16x8 Bh = *reinterpret_cast<const f16x8*>(bth + bo);
      #pragma unroll
      for (int m = 0; m < 2; ++m)
        acc[m][nt] = __builtin_amdgcn_mfma_f32_16x16x32_f16(Ah[m], Bh, acc[m][nt], 0,0,0);
    }
  }

  // ---- epilogue: bias + ReLU + W2 dot; reduce 16 n-lanes; combine 8 waves ----
  float w2v[4], b1v[4];
  #pragma unroll
  for (int nt=0; nt<4; ++nt){
    const int n = q*64 + nt*16 + mrow;    // C: col = lane&15
    w2v[nt] = W2[n]; b1v[nt] = b1[n];
  }
  #pragma unroll
  for (int mt=0; mt<2; ++mt){
    #pragma unroll
    for (int r=0; r<4; ++r){
      float s = 0.f;
      #pragma unroll
      for (int nt=0; nt<4; ++nt)
        s += fmaxf(acc[mt][nt][r] + b1v[nt], 0.f) * w2v[nt];
      s += __shfl_xor(s, 1, 64);
      s += __shfl_xor(s, 2, 64);
      s += __shfl_xor(s, 4, 64);
      s += __shfl_xor(s, 8, 64);
      if (mrow == 0)
        sred[q*32 + mt*16 + kgrp*4 + r] = s;   // C: row = (lane>>4)*4 + reg
    }
  }
  __syncthreads();
  if (tid < MROWS){
    const int rr = brow + tid;
    float tot = b2[0];
    #pragma unroll
    for (int w = 0; w < 8; ++w) tot += sred[w*32 + tid];
    const float m = 1.f / (1.f + expf(-tot));
    mask_out[rr] = m;
    atomicAdd(&cnt_all[s2g[rr]], 1);
    if (fabsf(m - 0.4f) < RMARG || fabsf(m - 0.3f) < RMARG){
      const int p = atomicAdd(rcnt, 1);
      if (p < RCAP) rlist[p] = rr;
    }
  }
}

// ---------------- refine: batch-32 exact fp32 (one W1 stream per 32 rows) ----------------
// 512 thr: thread t owns hidden unit t. Stage 32 rows in LDS; per k one coalesced
// 2KB W1 row feeds 32 FMAs (arow[r][k] = LDS same-address broadcast, free).
__global__ __launch_bounds__(512) void refine_kernel(
    const float* __restrict__ hsub, const float* __restrict__ W1,
    const float* __restrict__ b1, const float* __restrict__ W2,
    const float* __restrict__ b2, const int* __restrict__ rlist,
    const int* __restrict__ rcnt, float* __restrict__ mask_out)
{
  __shared__ float arow[32][260];   // 33,280 B (pad 260)
  __shared__ float redm[8][32];
  const int t = threadIdx.x;
  const int lane = t & 63, w = t >> 6;
  const int n = min(rcnt[0], RCAP);
  const int nbatch = (n + 31) >> 5;
  for (int b = blockIdx.x; b < nbatch; b += gridDim.x){
    const int rbase = b*32;
    const int nr = min(32, n - rbase);
    __syncthreads();                       // arow safe to overwrite
    #pragma unroll
    for (int i = 0; i < 4; ++i){
      const int c = i*512 + t;             // float4 chunk 0..2047
      const int r = c >> 6;                // row slot 0..31
      const int col = (c & 63)*4;
      const int row = rlist[rbase + ((r < nr) ? r : 0)];
      const float4 v = *reinterpret_cast<const float4*>(hsub + (size_t)row*DIM + col);
      *reinterpret_cast<float4*>(&arow[r][col]) = v;
    }
    __syncthreads();
    float y[32];
    #pragma unroll
    for (int r = 0; r < 32; ++r) y[r] = 0.f;
    #pragma unroll 4
    for (int k = 0; k < 256; ++k){
      const float w1v = W1[(size_t)k*512 + t];
      #pragma unroll
      for (int r = 0; r < 32; ++r)
        y[r] = fmaf(arow[r][k], w1v, y[r]);
    }
    const float b1v = b1[t], w2v = W2[t];
    #pragma unroll
    for (int r = 0; r < 32; ++r){
      float s = fmaxf(y[r] + b1v, 0.f) * w2v;
      s = wave_reduce(s);
      if (lane == 0) redm[w][r] = s;
    }
    __syncthreads();
    if (t < nr){
      float tot = b2[0];
      #pragma unroll
      for (int ww = 0; ww < 8; ++ww) tot += redm[ww][t];
      mask_out[rlist[rbase + t]] = 1.f / (1.f + expf(-tot));
    }
  }
}

// ---------------- CSR build: scan + fill ----------------
__global__ __launch_bounds__(1024) void scan_kernel(const int* __restrict__ cnt,
                                                    int* __restrict__ offs,
                                                    int* __restrict__ cursor){
  __shared__ int buf[1024];
  const int t = threadIdx.x;
  const int c0 = cnt[t*4], c1 = cnt[t*4+1], c2 = cnt[t*4+2], c3 = cnt[t*4+3];
  const int s = c0+c1+c2+c3;
  buf[t] = s; __syncthreads();
  for (int d = 1; d < 1024; d <<= 1){
    int v = (t >= d) ? buf[t-d] : 0;
    __syncthreads();
    buf[t] += v;
    __syncthreads();
  }
  const int excl = buf[t] - s;
  const int o0 = excl, o1 = excl+c0, o2 = o1+c1, o3 = o2+c2;
  offs[t*4]=o0; offs[t*4+1]=o1; offs[t*4+2]=o2; offs[t*4+3]=o3;
  cursor[t*4]=o0; cursor[t*4+1]=o1; cursor[t*4+2]=o2; cursor[t*4+3]=o3;
  if (t == 1023) offs[4096] = buf[1023];
}

__global__ void fill_kernel(const int* __restrict__ s2g, int* __restrict__ cursor,
                            int* __restrict__ list){
  const int i = blockIdx.x*blockDim.x + threadIdx.x;
  if (i < N_SUB){
    const int g = s2g[i];
    const int p = atomicAdd(&cursor[g], 1);
    list[p] = i;
  }
}

// ---------------- kernel C: per-graph masked means (replica-spread atomics) ----------------
__global__ __launch_bounds__(256) void graph_means(
    const float* __restrict__ hsub, const float* __restrict__ mask,
    const int* __restrict__ list, const int* __restrict__ offs,
    const float* __restrict__ hgraph, const float* __restrict__ Wc,
    const float* __restrict__ bc, unsigned short* __restrict__ hatAb,
    float* __restrict__ S32, float* __restrict__ Se32,
    int* __restrict__ nzflags, int* __restrict__ counters,
    float* __restrict__ out)
{
  __shared__ int   sidx[256];
  __shared__ unsigned char sflag[256];
  __shared__ float wr4[4][4];
  __shared__ float wrc[TCLS][4];
  const int g = blockIdx.x;
  const int t = threadIdx.x;
  const int w = t >> 6, lane = t & 63;
  const int start = offs[g], end = offs[g+1];
  const int cnt = end - start;
  float sv = 0.f, sev = 0.f;
  int cv = 0, ce = 0;
  for (int base = 0; base < cnt; base += 256){
    const int nb = min(256, cnt - base);
    __syncthreads();
    if (t < nb){
      const int i = list[start + base + t];
      sidx[t] = i;
      const float m = mask[i];
      sflag[t] = (m > 0.4f) ? 1 : ((m <= 0.3f) ? 2 : 0);
    }
    __syncthreads();
    for (int p = 0; p < nb; p += 4){
      const int lim = nb - p;
      const int i0 = sidx[p];
      const int i1 = (lim > 1) ? sidx[p+1] : i0;
      const int i2 = (lim > 2) ? sidx[p+2] : i0;
      const int i3 = (lim > 3) ? sidx[p+3] : i0;
      const int f0 = sflag[p];
      const int f1 = (lim > 1) ? sflag[p+1] : 0;
      const int f2 = (lim > 2) ? sflag[p+2] : 0;
      const int f3 = (lim > 3) ? sflag[p+3] : 0;
      const float v0 = hsub[(size_t)i0*DIM + t];
      const float v1 = hsub[(size_t)i1*DIM + t];
      const float v2 = hsub[(size_t)i2*DIM + t];
      const float v3 = hsub[(size_t)i3*DIM + t];
      if (f0==1){ sv+=v0; cv++; } else if (f0==2){ sev+=v0; ce++; }
      if (f1==1){ sv+=v1; cv++; } else if (f1==2){ sev+=v1; ce++; }
      if (f2==1){ sv+=v2; cv++; } else if (f2==2){ sev+=v2; ce++; }
      if (f3==1){ sv+=v3; cv++; } else if (f3==2){ sev+=v3; ce++; }
    }
  }
  __syncthreads();
  const float aligned = sv  / fmaxf((float)cv, 1.f);
  const float envv    = sev / fmaxf((float)ce, 1.f);
  float r0 = wave_reduce(aligned*aligned);
  float r1 = wave_reduce(envv*envv);
  float r2 = wave_reduce(aligned != 0.f ? 1.f : 0.f);
  float r3 = wave_reduce(envv    != 0.f ? 1.f : 0.f);
  if (lane == 0){ wr4[w][0]=r0; wr4[w][1]=r1; wr4[w][2]=r2; wr4[w][3]=r3; }
  __syncthreads();
  const float an2  = wr4[0][0]+wr4[1][0]+wr4[2][0]+wr4[3][0];
  const float en2  = wr4[0][1]+wr4[1][1]+wr4[2][1]+wr4[3][1];
  const float nzpf = wr4[0][2]+wr4[1][2]+wr4[2][2]+wr4[3][2];
  const float nzef = wr4[0][3]+wr4[1][3]+wr4[2][3]+wr4[3][3];
  const bool nzp = nzpf > 0.f, nze = nzef > 0.f;
  const float an = fmaxf(sqrtf(an2), 1e-8f);
  const float en = fmaxf(sqrtf(en2), 1e-8f);
  const float ha = aligned / an;
  hatAb[(size_t)g*DIM + t] = (unsigned short)bf16_rne(ha);
  atomicAdd(&S32[((g & (NREP-1)) << 8) + t], ha);
  if (nze) atomicAdd(&Se32[((g & (NREP-1)) << 8) + t], envv / en);
  if (t == 0){
    nzflags[g] = nzp ? 1 : 0;
    if (nzp) atomicAdd(&counters[0], 1);
    if (nze) atomicAdd(&counters[1], 1);
  }
  const float hg = hgraph[(size_t)g*DIM + t];
  #pragma unroll
  for (int c = 0; c < TCLS; ++c){
    float part = hg*Wc[t*TCLS+c] + aligned*Wc[(DIM+t)*TCLS+c];
    part = wave_reduce(part);
    if (lane == 0) wrc[c][w] = part;
  }
  __syncthreads();
  if (t < TCLS)
    out[g*TCLS + t] = wrc[t][0]+wrc[t][1]+wrc[t][2]+wrc[t][3] + bc[t];
}

// ---------------- combine: fold S/Se replicas (16 blocks x 2 reps + atomic merge) ----------------
__global__ __launch_bounds__(256) void combine_kernel(const float* __restrict__ S32,
                                                      const float* __restrict__ Se32,
                                                      float* __restrict__ S,
                                                      float* __restrict__ Se){
  const int b = blockIdx.x;       // 0..15
  const int t = threadIdx.x;
  float s = 0.f, se = 0.f;
  #pragma unroll
  for (int r = 0; r < 2; ++r){
    s  += S32[(b*2 + r)*DIM + t];
    se += Se32[(b*2 + r)*DIM + t];
  }
  atomicAdd(&S[t], s);
  atomicAdd(&Se[t], se);
}

// ---------------- kernel D: contrastive loss via rank-1 identity ----------------
__global__ __launch_bounds__(256) void loss_kernel(
    const unsigned short* __restrict__ hatAb, const float* __restrict__ S,
    const float* __restrict__ Se, const int* __restrict__ nzflags,
    const int* __restrict__ counters, float* __restrict__ loss_p)
{
  __shared__ float wr[4][2];
  const int g = blockIdx.x, t = threadIdx.x;
  const int w = t >> 6, lane = t & 63;
  const float ha = bf16_to_f((short)hatAb[(size_t)g*DIM + t]);
  float p0 = wave_reduce(ha*S[t]);
  float p1 = wave_reduce(ha*Se[t]);
  if (lane == 0){ wr[w][0] = p0; wr[w][1] = p1; }
  __syncthreads();
  if (t == 0){
    const float dS  = wr[0][0]+wr[1][0]+wr[2][0]+wr[3][0];
    const float dSe = wr[0][1]+wr[1][1]+wr[2][1]+wr[3][1];
    const int nzp_cnt = counters[0];
    const int nenv = counters[1];
    const float pos_num = fmaxf((float)(nzp_cnt - 1), 1.f);
    const float positive = (4096.f - dS) / pos_num;
    const float negative = ((float)nenv - dSe) / fmaxf((float)nenv, 1.f);
    float contrib = fmaxf(positive - negative + 1.f, 0.f);
    contrib *= (nzflags[g] ? 1.f : 0.f) * ((nenv > 0) ? 1.f : 0.f);
    atomicAdd(&loss_p[g & 63], contrib * (1.f/4096.f));
  }
}

// ---------------- final: fold loss partials ----------------
__global__ void final_loss(const float* __restrict__ loss_p, float* __restrict__ loss){
  const int t = threadIdx.x;    // 64 threads
  float v = loss_p[t];
  v = wave_reduce(v);
  if (t == 0) loss[0] = v;
}

// ---------------- launch ----------------
extern "C" void kernel_launch(void* const* d_in, const int* in_sizes, int n_in,
                              void* d_out, int out_size, void* d_ws, size_t ws_size,
                              hipStream_t stream) {
  const float* h_graph = (const float*)d_in[0];
  const float* h_sub   = (const float*)d_in[1];
  const float* W1      = (const float*)d_in[2];
  const float* b1      = (const float*)d_in[3];
  const float* W2      = (const float*)d_in[4];
  const float* b2      = (const float*)d_in[5];
  const float* Wc      = (const float*)d_in[6];
  const float* bc      = (const float*)d_in[7];
  const int*   s2g     = (const int*)d_in[8];

  float* out  = (float*)d_out;          // [4096,10]
  float* loss = out + N_GR*TCLS;        // scalar
  float* mask = loss + 1;               // [200000]

  // workspace layout — ~3.4 MB (proven-safe envelope 5.06 MB)
  char* ws = (char*)d_ws;
  unsigned short* bth = (unsigned short*)ws;           // 256 KB (fp16 plane)
  unsigned short* hatAb = bth + HID*DIM;               // 2 MB
  int* cnt_all  = (int*)(hatAb + (size_t)N_GR*DIM);    // 4096
  int* offs     = cnt_all + N_GR;                      // 4097
  int* cursor   = offs + N_GR + 1;                     // 4096
  int* list     = cursor + N_GR;                       // 200000
  int* nzflags  = list + N_SUB;                        // 4096
  int* counters = nzflags + N_GR;                      // 2
  int* rcnt     = counters + 2;                        // 1
  int* rlist    = rcnt + 1;                            // 16384
  float* S      = (float*)(rlist + RCAP);              // 256
  float* Se     = S + DIM;                             // 256
  float* S32    = Se + DIM;                            // 32*256 (32 KB)
  float* Se32   = S32 + NREP*DIM;                      // 32*256 (32 KB)
  float* loss_p = Se32 + NREP*DIM;                     // 64

  hipLaunchKernelGGL(bconv_kernel, dim3(HID*DIM/256), dim3(256), 0, stream,
                     W1, bth, cnt_all, S32, Se32, S, Se, counters, loss_p, rcnt);
  hipLaunchKernelGGL(mask_gemm, dim3(N_SUB/MROWS), dim3(512), 0, stream,
                     h_sub, bth, b1, W2, b2, s2g, mask, cnt_all, rlist, rcnt);
  hipLaunchKernelGGL(refine_kernel, dim3(256), dim3(512), 0, stream,
                     h_sub, W1, b1, W2, b2, rlist, rcnt, mask);
  hipLaunchKernelGGL(scan_kernel, dim3(1), dim3(1024), 0, stream,
                     cnt_all, offs, cursor);
  hipLaunchKernelGGL(fill_kernel, dim3((N_SUB+255)/256), dim3(256), 0, stream,
                     s2g, cursor, list);
  hipLaunchKernelGGL(graph_means, dim3(N_GR), dim3(256), 0, stream,
                     h_sub, mask, list, offs, h_graph, Wc, bc,
                     hatAb, S32, Se32, nzflags, counters, out);
  hipLaunchKernelGGL(combine_kernel, dim3(16), dim3(256), 0, stream,
                     S32, Se32, S, Se);
  hipLaunchKernelGGL(loss_kernel, dim3(N_GR), dim3(256), 0, stream,
                     hatAb, S, Se, nzflags, counters, loss_p);
  hipLaunchKernelGGL(final_loss, dim3(1), dim3(64), 0, stream,
                     loss_p, loss);
}

// Round 28
// 329.515 us; speedup vs baseline: 1.4718x; 1.3141x over previous
//
#include <hip/hip_runtime.h>

#define N_SUB 200000
#define N_GR  4096
#define DIM   256
#define HID   512
#define TCLS  10
#define MROWS 32             // 6250 * 32 = 200000 exactly; acc[2][4]=32 AGPR
#define RCAP  32768          // raised: r27 evidence shows band ~16k at 4e-3
#define RMARG 2e-3f          // 20-sigma of fp16 mask error (sigma ~1e-4)
#define NREP  32             // S/Se replica count

typedef __attribute__((ext_vector_type(8))) _Float16 f16x8;
typedef __attribute__((ext_vector_type(4))) float f32x4;

__device__ __forceinline__ short bf16_rne(float x){
  unsigned u = __builtin_bit_cast(unsigned, x);
  unsigned r = (u + 0x7FFFu + ((u >> 16) & 1u)) >> 16;
  return (short)r;
}
__device__ __forceinline__ float bf16_to_f(short h){
  unsigned u = ((unsigned)(unsigned short)h) << 16;
  return __builtin_bit_cast(float, u);
}
__device__ __forceinline__ unsigned short f16_bits(float x){
  return __builtin_bit_cast(unsigned short, (_Float16)x);   // v_cvt_f16_f32, RNE
}
__device__ __forceinline__ float wave_reduce(float v){
  #pragma unroll
  for (int d = 1; d < 64; d <<= 1) v += __shfl_xor(v, d, 64);
  return v;
}
// swizzled fragment-major A granule index (16B granules = 8 halfs); ks 0..7, mt 0..1
__device__ __forceinline__ int a_gran(int mt, int mrow, int ks, int kgrp){
  return (((((mt*8 + ks)*4 + kgrp)*2 + (mrow>>3)) << 3)
          | ((mrow & 7) ^ ((ks & 3) << 1) ^ (kgrp & 1)));
}

// ---------------- bconv + fused init: W1 -> fragment-major fp16 ----------------
__global__ __launch_bounds__(256) void bconv_kernel(const float* __restrict__ W1,
                                                    unsigned short* __restrict__ bth,
                                                    int* cnt_all, float* S32, float* Se32,
                                                    float* S, float* Se,
                                                    int* counters, float* loss_p, int* rcnt){
  const int i = blockIdx.x*256 + threadIdx.x;
  if (i < N_GR) cnt_all[i] = 0;
  if (i < NREP*DIM){ S32[i] = 0.f; Se32[i] = 0.f; }
  if (i < DIM){ S[i] = 0.f; Se[i] = 0.f; }
  if (i < 64) loss_p[i] = 0.f;
  if (i < 2) counters[i] = 0;
  if (i == 0) rcnt[0] = 0;
  const int k = i >> 9;
  const int j = i & 511;
  const float x = W1[i];
  const int nt = j >> 4, mrow = j & 15;
  const int ksg = k >> 5, kgrp = (k >> 3) & 3, kk = k & 7;
  const int lane = kgrp*16 + mrow;
  const size_t dst = (((size_t)(nt*8 + ksg)*64 + lane) << 3) + kk;
  bth[dst] = f16_bits(x);
}

// ---------------- kernel A: single-plane fp16 MFMA, 32 rows/block ----------------
__global__ __launch_bounds__(512, 4) void mask_gemm(
    const float* __restrict__ hsub, const unsigned short* __restrict__ bth,
    const float* __restrict__ b1, const float* __restrict__ W2,
    const float* __restrict__ b2, const int* __restrict__ s2g,
    float* __restrict__ mask_out, int* __restrict__ cnt_all,
    int* __restrict__ rlist, int* __restrict__ rcnt)
{
  __shared__ unsigned short a_f[8192];  // 16 KB swizzled fragment-major (32 rows x 256 k)
  __shared__ float sred[256];           // 1 KB -> 17 KB total
  const int tid = threadIdx.x;
  const int lane = tid & 63;
  const int q = tid >> 6;
  const int mrow = lane & 15;
  const int kgrp = lane >> 4;
  const int brow = blockIdx.x*MROWS;

  f32x4 acc[2][4];
  #pragma unroll
  for (int mt=0; mt<2; ++mt)
    #pragma unroll
    for (int nt=0; nt<4; ++nt) acc[mt][nt] = (f32x4){0.f,0.f,0.f,0.f};

  // ---- stage: 4 hoisted float4 loads per thread, fp32 -> fp16 ----
  const float* __restrict__ gbase = hsub + (size_t)brow*DIM;
  {
    float4 g[4];
    #pragma unroll
    for (int i = 0; i < 4; ++i){
      const int idx = i*512 + tid;               // float4 chunk 0..2047
      g[i] = *reinterpret_cast<const float4*>(gbase + (size_t)idx*4);
    }
    #pragma unroll
    for (int i = 0; i < 4; ++i){
      const int idx = i*512 + tid;
      const int rr = idx >> 6;                   // row 0..31
      const int ch = idx & 63;                   // full-K chunk 0..63
      const float4 v = g[i];
      const int so = a_gran(rr>>4, rr&15, ch>>3, (ch>>1)&3)*8 + (ch&1)*4;
      *reinterpret_cast<ushort4*>(&a_f[so]) =
          make_ushort4(f16_bits(v.x), f16_bits(v.y), f16_bits(v.z), f16_bits(v.w));
    }
  }
  __syncthreads();

  f16x8 Ah[2];
  #pragma unroll
  for (int ks = 0; ks < 8; ++ks){
    #pragma unroll
    for (int m = 0; m < 2; ++m){
      const int so = a_gran(m, mrow, ks, kgrp)*8;
      Ah[m] = *reinterpret_cast<const f16x8*>(&a_f[so]);
    }
    #pragma unroll
    for (int nt = 0; nt < 4; ++nt){
      const size_t bo = (((size_t)((q*4+nt)*8 + ks)*64 + lane) << 3);
      const f16x8 Bh = *reinterpret_cast<const f16x8*>(bth + bo);
      #pragma unroll
      for (int m = 0; m < 2; ++m)
        acc[m][nt] = __builtin_amdgcn_mfma_f32_16x16x32_f16(Ah[m], Bh, acc[m][nt], 0,0,0);
    }
  }

  // ---- epilogue: bias + ReLU + W2 dot; reduce 16 n-lanes; combine 8 waves ----
  float w2v[4], b1v[4];
  #pragma unroll
  for (int nt=0; nt<4; ++nt){
    const int n = q*64 + nt*16 + mrow;    // C: col = lane&15
    w2v[nt] = W2[n]; b1v[nt] = b1[n];
  }
  #pragma unroll
  for (int mt=0; mt<2; ++mt){
    #pragma unroll
    for (int r=0; r<4; ++r){
      float s = 0.f;
      #pragma unroll
      for (int nt=0; nt<4; ++nt)
        s += fmaxf(acc[mt][nt][r] + b1v[nt], 0.f) * w2v[nt];
      s += __shfl_xor(s, 1, 64);
      s += __shfl_xor(s, 2, 64);
      s += __shfl_xor(s, 4, 64);
      s += __shfl_xor(s, 8, 64);
      if (mrow == 0)
        sred[q*32 + mt*16 + kgrp*4 + r] = s;   // C: row = (lane>>4)*4 + reg
    }
  }
  __syncthreads();
  if (tid < MROWS){
    const int rr = brow + tid;
    float tot = b2[0];
    #pragma unroll
    for (int w = 0; w < 8; ++w) tot += sred[w*32 + tid];
    const float m = 1.f / (1.f + expf(-tot));
    mask_out[rr] = m;
    atomicAdd(&cnt_all[s2g[rr]], 1);
    if (fabsf(m - 0.4f) < RMARG || fabsf(m - 0.3f) < RMARG){
      const int p = atomicAdd(rcnt, 1);
      if (p < RCAP) rlist[p] = rr;
    }
  }
}

// ---------------- refine: batch-32, k-major transposed row tile ----------------
// Per k: one coalesced W1 row (2KB) + 8 ds_read_b128 broadcasts (was 32 b32) + 32 FMA.
__global__ __launch_bounds__(512) void refine_kernel(
    const float* __restrict__ hsub, const float* __restrict__ W1,
    const float* __restrict__ b1, const float* __restrict__ W2,
    const float* __restrict__ b2, const int* __restrict__ rlist,
    const int* __restrict__ rcnt, float* __restrict__ mask_out)
{
  __shared__ __align__(16) float arowT[256][36];  // k-major, 36-float stride: 36,864 B
  __shared__ float redm[8][32];
  const int t = threadIdx.x;
  const int lane = t & 63, w = t >> 6;
  const int n = min(rcnt[0], RCAP);
  const int nbatch = (n + 31) >> 5;
  for (int b = blockIdx.x; b < nbatch; b += gridDim.x){
    const int rbase = b*32;
    const int nr = min(32, n - rbase);
    __syncthreads();                       // arowT safe to overwrite
    #pragma unroll
    for (int i = 0; i < 4; ++i){
      const int c = i*512 + t;             // float4 chunk 0..2047
      const int r = c >> 6;                // row slot 0..31
      const int k0 = (c & 63)*4;
      const int row = rlist[rbase + ((r < nr) ? r : 0)];
      const float4 v = *reinterpret_cast<const float4*>(hsub + (size_t)row*DIM + k0);
      arowT[k0  ][r] = v.x;
      arowT[k0+1][r] = v.y;
      arowT[k0+2][r] = v.z;
      arowT[k0+3][r] = v.w;
    }
    __syncthreads();
    float y[32];
    #pragma unroll
    for (int r = 0; r < 32; ++r) y[r] = 0.f;
    #pragma unroll 2
    for (int k = 0; k < 256; ++k){
      const float w1v = W1[(size_t)k*512 + t];
      const float4* __restrict__ ap = reinterpret_cast<const float4*>(&arowT[k][0]);
      #pragma unroll
      for (int rq = 0; rq < 8; ++rq){
        const float4 a4 = ap[rq];
        y[rq*4+0] = fmaf(a4.x, w1v, y[rq*4+0]);
        y[rq*4+1] = fmaf(a4.y, w1v, y[rq*4+1]);
        y[rq*4+2] = fmaf(a4.z, w1v, y[rq*4+2]);
        y[rq*4+3] = fmaf(a4.w, w1v, y[rq*4+3]);
      }
    }
    const float b1v = b1[t], w2v = W2[t];
    #pragma unroll
    for (int r = 0; r < 32; ++r){
      float s = fmaxf(y[r] + b1v, 0.f) * w2v;
      s = wave_reduce(s);
      if (lane == 0) redm[w][r] = s;
    }
    __syncthreads();
    if (t < nr){
      float tot = b2[0];
      #pragma unroll
      for (int ww = 0; ww < 8; ++ww) tot += redm[ww][t];
      mask_out[rlist[rbase + t]] = 1.f / (1.f + expf(-tot));
    }
  }
}

// ---------------- CSR build: scan + fill ----------------
__global__ __launch_bounds__(1024) void scan_kernel(const int* __restrict__ cnt,
                                                    int* __restrict__ offs,
                                                    int* __restrict__ cursor){
  __shared__ int buf[1024];
  const int t = threadIdx.x;
  const int c0 = cnt[t*4], c1 = cnt[t*4+1], c2 = cnt[t*4+2], c3 = cnt[t*4+3];
  const int s = c0+c1+c2+c3;
  buf[t] = s; __syncthreads();
  for (int d = 1; d < 1024; d <<= 1){
    int v = (t >= d) ? buf[t-d] : 0;
    __syncthreads();
    buf[t] += v;
    __syncthreads();
  }
  const int excl = buf[t] - s;
  const int o0 = excl, o1 = excl+c0, o2 = o1+c1, o3 = o2+c2;
  offs[t*4]=o0; offs[t*4+1]=o1; offs[t*4+2]=o2; offs[t*4+3]=o3;
  cursor[t*4]=o0; cursor[t*4+1]=o1; cursor[t*4+2]=o2; cursor[t*4+3]=o3;
  if (t == 1023) offs[4096] = buf[1023];
}

__global__ void fill_kernel(const int* __restrict__ s2g, int* __restrict__ cursor,
                            int* __restrict__ list){
  const int i = blockIdx.x*blockDim.x + threadIdx.x;
  if (i < N_SUB){
    const int g = s2g[i];
    const int p = atomicAdd(&cursor[g], 1);
    list[p] = i;
  }
}

// ---------------- kernel C: per-graph masked means (replica-spread atomics) ----------------
__global__ __launch_bounds__(256) void graph_means(
    const float* __restrict__ hsub, const float* __restrict__ mask,
    const int* __restrict__ list, const int* __restrict__ offs,
    const float* __restrict__ hgraph, const float* __restrict__ Wc,
    const float* __restrict__ bc, unsigned short* __restrict__ hatAb,
    float* __restrict__ S32, float* __restrict__ Se32,
    int* __restrict__ nzflags, int* __restrict__ counters,
    float* __restrict__ out)
{
  __shared__ int   sidx[256];
  __shared__ unsigned char sflag[256];
  __shared__ float wr4[4][4];
  __shared__ float wrc[TCLS][4];
  const int g = blockIdx.x;
  const int t = threadIdx.x;
  const int w = t >> 6, lane = t & 63;
  const int start = offs[g], end = offs[g+1];
  const int cnt = end - start;
  float sv = 0.f, sev = 0.f;
  int cv = 0, ce = 0;
  for (int base = 0; base < cnt; base += 256){
    const int nb = min(256, cnt - base);
    __syncthreads();
    if (t < nb){
      const int i = list[start + base + t];
      sidx[t] = i;
      const float m = mask[i];
      sflag[t] = (m > 0.4f) ? 1 : ((m <= 0.3f) ? 2 : 0);
    }
    __syncthreads();
    for (int p = 0; p < nb; p += 4){
      const int lim = nb - p;
      const int i0 = sidx[p];
      const int i1 = (lim > 1) ? sidx[p+1] : i0;
      const int i2 = (lim > 2) ? sidx[p+2] : i0;
      const int i3 = (lim > 3) ? sidx[p+3] : i0;
      const int f0 = sflag[p];
      const int f1 = (lim > 1) ? sflag[p+1] : 0;
      const int f2 = (lim > 2) ? sflag[p+2] : 0;
      const int f3 = (lim > 3) ? sflag[p+3] : 0;
      const float v0 = hsub[(size_t)i0*DIM + t];
      const float v1 = hsub[(size_t)i1*DIM + t];
      const float v2 = hsub[(size_t)i2*DIM + t];
      const float v3 = hsub[(size_t)i3*DIM + t];
      if (f0==1){ sv+=v0; cv++; } else if (f0==2){ sev+=v0; ce++; }
      if (f1==1){ sv+=v1; cv++; } else if (f1==2){ sev+=v1; ce++; }
      if (f2==1){ sv+=v2; cv++; } else if (f2==2){ sev+=v2; ce++; }
      if (f3==1){ sv+=v3; cv++; } else if (f3==2){ sev+=v3; ce++; }
    }
  }
  __syncthreads();
  const float aligned = sv  / fmaxf((float)cv, 1.f);
  const float envv    = sev / fmaxf((float)ce, 1.f);
  float r0 = wave_reduce(aligned*aligned);
  float r1 = wave_reduce(envv*envv);
  float r2 = wave_reduce(aligned != 0.f ? 1.f : 0.f);
  float r3 = wave_reduce(envv    != 0.f ? 1.f : 0.f);
  if (lane == 0){ wr4[w][0]=r0; wr4[w][1]=r1; wr4[w][2]=r2; wr4[w][3]=r3; }
  __syncthreads();
  const float an2  = wr4[0][0]+wr4[1][0]+wr4[2][0]+wr4[3][0];
  const float en2  = wr4[0][1]+wr4[1][1]+wr4[2][1]+wr4[3][1];
  const float nzpf = wr4[0][2]+wr4[1][2]+wr4[2][2]+wr4[3][2];
  const float nzef = wr4[0][3]+wr4[1][3]+wr4[2][3]+wr4[3][3];
  const bool nzp = nzpf > 0.f, nze = nzef > 0.f;
  const float an = fmaxf(sqrtf(an2), 1e-8f);
  const float en = fmaxf(sqrtf(en2), 1e-8f);
  const float ha = aligned / an;
  hatAb[(size_t)g*DIM + t] = (unsigned short)bf16_rne(ha);
  atomicAdd(&S32[((g & (NREP-1)) << 8) + t], ha);
  if (nze) atomicAdd(&Se32[((g & (NREP-1)) << 8) + t], envv / en);
  if (t == 0){
    nzflags[g] = nzp ? 1 : 0;
    if (nzp) atomicAdd(&counters[0], 1);
    if (nze) atomicAdd(&counters[1], 1);
  }
  const float hg = hgraph[(size_t)g*DIM + t];
  #pragma unroll
  for (int c = 0; c < TCLS; ++c){
    float part = hg*Wc[t*TCLS+c] + aligned*Wc[(DIM+t)*TCLS+c];
    part = wave_reduce(part);
    if (lane == 0) wrc[c][w] = part;
  }
  __syncthreads();
  if (t < TCLS)
    out[g*TCLS + t] = wrc[t][0]+wrc[t][1]+wrc[t][2]+wrc[t][3] + bc[t];
}

// ---------------- combine: fold S/Se replicas (16 blocks x 2 reps + atomic merge) ----------------
__global__ __launch_bounds__(256) void combine_kernel(const float* __restrict__ S32,
                                                      const float* __restrict__ Se32,
                                                      float* __restrict__ S,
                                                      float* __restrict__ Se){
  const int b = blockIdx.x;       // 0..15
  const int t = threadIdx.x;
  float s = 0.f, se = 0.f;
  #pragma unroll
  for (int r = 0; r < 2; ++r){
    s  += S32[(b*2 + r)*DIM + t];
    se += Se32[(b*2 + r)*DIM + t];
  }
  atomicAdd(&S[t], s);
  atomicAdd(&Se[t], se);
}

// ---------------- kernel D: contrastive loss via rank-1 identity ----------------
__global__ __launch_bounds__(256) void loss_kernel(
    const unsigned short* __restrict__ hatAb, const float* __restrict__ S,
    const float* __restrict__ Se, const int* __restrict__ nzflags,
    const int* __restrict__ counters, float* __restrict__ loss_p)
{
  __shared__ float wr[4][2];
  const int g = blockIdx.x, t = threadIdx.x;
  const int w = t >> 6, lane = t & 63;
  const float ha = bf16_to_f((short)hatAb[(size_t)g*DIM + t]);
  float p0 = wave_reduce(ha*S[t]);
  float p1 = wave_reduce(ha*Se[t]);
  if (lane == 0){ wr[w][0] = p0; wr[w][1] = p1; }
  __syncthreads();
  if (t == 0){
    const float dS  = wr[0][0]+wr[1][0]+wr[2][0]+wr[3][0];
    const float dSe = wr[0][1]+wr[1][1]+wr[2][1]+wr[3][1];
    const int nzp_cnt = counters[0];
    const int nenv = counters[1];
    const float pos_num = fmaxf((float)(nzp_cnt - 1), 1.f);
    const float positive = (4096.f - dS) / pos_num;
    const float negative = ((float)nenv - dSe) / fmaxf((float)nenv, 1.f);
    float contrib = fmaxf(positive - negative + 1.f, 0.f);
    contrib *= (nzflags[g] ? 1.f : 0.f) * ((nenv > 0) ? 1.f : 0.f);
    atomicAdd(&loss_p[g & 63], contrib * (1.f/4096.f));
  }
}

// ---------------- final: fold loss partials ----------------
__global__ void final_loss(const float* __restrict__ loss_p, float* __restrict__ loss){
  const int t = threadIdx.x;    // 64 threads
  float v = loss_p[t];
  v = wave_reduce(v);
  if (t == 0) loss[0] = v;
}

// ---------------- launch ----------------
extern "C" void kernel_launch(void* const* d_in, const int* in_sizes, int n_in,
                              void* d_out, int out_size, void* d_ws, size_t ws_size,
                              hipStream_t stream) {
  const float* h_graph = (const float*)d_in[0];
  const float* h_sub   = (const float*)d_in[1];
  const float* W1      = (const float*)d_in[2];
  const float* b1      = (const float*)d_in[3];
  const float* W2      = (const float*)d_in[4];
  const float* b2      = (const float*)d_in[5];
  const float* Wc      = (const float*)d_in[6];
  const float* bc      = (const float*)d_in[7];
  const int*   s2g     = (const int*)d_in[8];

  float* out  = (float*)d_out;          // [4096,10]
  float* loss = out + N_GR*TCLS;        // scalar
  float* mask = loss + 1;               // [200000]

  // workspace layout — ~3.5 MB (proven-safe envelope 5.06 MB)
  char* ws = (char*)d_ws;
  unsigned short* bth = (unsigned short*)ws;           // 256 KB (fp16 plane)
  unsigned short* hatAb = bth + HID*DIM;               // 2 MB
  int* cnt_all  = (int*)(hatAb + (size_t)N_GR*DIM);    // 4096
  int* offs     = cnt_all + N_GR;                      // 4097
  int* cursor   = offs + N_GR + 1;                     // 4096
  int* list     = cursor + N_GR;                       // 200000
  int* nzflags  = list + N_SUB;                        // 4096
  int* counters = nzflags + N_GR;                      // 2
  int* rcnt     = counters + 2;                        // 1
  int* rlist    = rcnt + 1;                            // 32768 (128 KB)
  float* S      = (float*)(rlist + RCAP);              // 256
  float* Se     = S + DIM;                             // 256
  float* S32    = Se + DIM;                            // 32*256 (32 KB)
  float* Se32   = S32 + NREP*DIM;                      // 32*256 (32 KB)
  float* loss_p = Se32 + NREP*DIM;                     // 64

  hipLaunchKernelGGL(bconv_kernel, dim3(HID*DIM/256), dim3(256), 0, stream,
                     W1, bth, cnt_all, S32, Se32, S, Se, counters, loss_p, rcnt);
  hipLaunchKernelGGL(mask_gemm, dim3(N_SUB/MROWS), dim3(512), 0, stream,
                     h_sub, bth, b1, W2, b2, s2g, mask, cnt_all, rlist, rcnt);
  hipLaunchKernelGGL(refine_kernel, dim3(256), dim3(512), 0, stream,
                     h_sub, W1, b1, W2, b2, rlist, rcnt, mask);
  hipLaunchKernelGGL(scan_kernel, dim3(1), dim3(1024), 0, stream,
                     cnt_all, offs, cursor);
  hipLaunchKernelGGL(fill_kernel, dim3((N_SUB+255)/256), dim3(256), 0, stream,
                     s2g, cursor, list);
  hipLaunchKernelGGL(graph_means, dim3(N_GR), dim3(256), 0, stream,
                     h_sub, mask, list, offs, h_graph, Wc, bc,
                     hatAb, S32, Se32, nzflags, counters, out);
  hipLaunchKernelGGL(combine_kernel, dim3(16), dim3(256), 0, stream,
                     S32, Se32, S, Se);
  hipLaunchKernelGGL(loss_kernel, dim3(N_GR), dim3(256), 0, stream,
                     hatAb, S, Se, nzflags, counters, loss_p);
  hipLaunchKernelGGL(final_loss, dim3(1), dim3(64), 0, stream,
                     loss_p, loss);
}